// Round 7
// baseline (298.022 us; speedup 1.0000x reference)
//
#include <hip/hip_runtime.h>
#include <math.h>

namespace {
constexpr int   BS_   = 64;
constexpr int   D_    = 768;
constexpr int   NVL_  = 192;            // 3*BS rows of vl_embeddings
constexpr int   NQ_   = 128;            // query rows (vl[64:])
constexpr int   CAP_  = 131072;
constexpr int   NCOL_ = NVL_ + CAP_;    // 131264 (the PRE dimension)
constexpr float THR_  = 0.5f;
constexpr float EPS_  = 1e-8f;

// workspace float offsets
constexpr int WS_QN   = 0;    // 128 query norms
constexpr int WS_SL   = 128;  // 1   global label sum
constexpr int WS_MN   = 160;  // 128 per-query min(sim_m)
constexpr int WS_MX   = 288;  // 128 per-query max(sim_m)
constexpr int WS_SS   = 416;  // 128 per-query sum(sim_m + 1)
constexpr int WS_SSL  = 544;  // 128 per-query sum((sim_m + 1)*label)
constexpr int WS_S0   = 672;  // 128 per-query sum(sim where selected)
constexpr int WS_CNT  = 800;  // 128 per-query count(selected)
constexpr int WS_ZERO = 1024; // 768 zero floats (safe OOB source)
constexpr int WS_QBF  = 2048; // 49152 floats: q bf16, 24 tiles of 8192 B (swizzled LDS image)

constexpr int TM    = 128;    // pre-rows per block
constexpr int BK    = 32;     // k per step
constexpr int NSTEP = D_ / BK;   // 24 steps, 12 pairs
}

using bf16x8 = __attribute__((ext_vector_type(8))) short;
using f32x4  = __attribute__((ext_vector_type(4))) float;

__device__ inline void atomicMinF(float* addr, float v) {
    if (v >= 0.f) atomicMin((int*)addr, __float_as_int(v));
    else          atomicMax((unsigned int*)addr, __float_as_uint(v));
}
__device__ inline void atomicMaxF(float* addr, float v) {
    if (v >= 0.f) atomicMax((int*)addr, __float_as_int(v));
    else          atomicMin((unsigned int*)addr, __float_as_uint(v));
}
// pack two f32 -> two bf16 (RNE) in one u32
__device__ inline unsigned pk2bf(float a, float b) {
    unsigned ua = __float_as_uint(a), ub = __float_as_uint(b);
    ua += 0x7fffu + ((ua >> 16) & 1u);
    ub += 0x7fffu + ((ub >> 16) & 1u);
    return (ua >> 16) | (ub & 0xffff0000u);
}

// ---------------- kernel 0: init accumulators + zero pad buffer ----------------
__global__ void lpe_init(float* ws) {
    int t = threadIdx.x;
    if (t < NQ_) {
        ws[WS_MN + t]  = INFINITY;
        ws[WS_MX + t]  = -INFINITY;
        ws[WS_SS + t]  = 0.f;
        ws[WS_SSL + t] = 0.f;
        ws[WS_S0 + t]  = 0.f;
        ws[WS_CNT + t] = 0.f;
    }
    if (t == 0) ws[WS_SL] = 0.f;
    for (int i = t; i < D_; i += 256) ws[WS_ZERO + i] = 0.f;
}

// ---------------- kernel 1: query norms + q bf16 image + global label sum ----------------
__global__ void lpe_prep(const float* __restrict__ vl,
                         const float* __restrict__ itm,
                         const float* __restrict__ expl,
                         float* ws) {
    __shared__ float red[256];
    int b = blockIdx.x, t = threadIdx.x;
    if (b < NQ_) {
        const float* row = vl + (size_t)(BS_ + b) * D_;
        float s = 0.f;
        for (int k = t; k < D_; k += 256) { float v = row[k]; s += v * v; }
        red[t] = s; __syncthreads();
        for (int o = 128; o > 0; o >>= 1) { if (t < o) red[t] += red[t + o]; __syncthreads(); }
        if (t == 0) ws[WS_QN + b] = sqrtf(red[0]);
        // swizzled bf16 image: tile s (8192 B) = [row][64 B], byte = (kk*2) ^ ((row>>1 & 3)<<4)
        unsigned* qbf = (unsigned*)(ws + WS_QBF);
        const int sw = ((b >> 1) & 3) << 4;
        for (int k2 = t; k2 < 384; k2 += 256) {
            const int k = 2 * k2, tile = k >> 5, kk = k & 31;
            const unsigned val = pk2bf(row[k], row[k + 1]);
            const int byte = tile * 8192 + b * 64 + (((kk * 2) ^ sw) & 63);
            qbf[byte >> 2] = val;
        }
    } else {
        int idx = (b - NQ_) * 256 + t;
        float s = 0.f;
        for (int j = idx; j < NCOL_; j += 256 * 256)
            s += (j < NVL_) ? itm[j] : expl[j - NVL_];
        red[t] = s; __syncthreads();
        for (int o = 128; o > 0; o >>= 1) { if (t < o) red[t] += red[t + o]; __syncthreads(); }
        if (t == 0) atomicAdd(ws + WS_SL, red[0]);
    }
}

// ---------------- kernel 2: reg-A bf16 MFMA, 2 steps/iter, 1 barrier/iter ----------------
// M = pre rows (128/block), N = 128 queries, K = 768.
__global__ __launch_bounds__(256, 3) void lpe_main(
        const float* __restrict__ vl, const float* __restrict__ score,
        const float* __restrict__ itm, const float* __restrict__ queue,
        const float* __restrict__ expl, const float* __restrict__ W,
        const float* __restrict__ bvec, float* ws) {
    __shared__ short Bs[4][NQ_][BK];    // 4 x 8 KB bf16 query tiles (swizzled rows)
    __shared__ float rn_s[TM], rsc_s[TM], lab_s[TM];
    __shared__ float qn_sh[NQ_], qsc_sh[NQ_];
    __shared__ float qmn[NQ_], qmx[NQ_], qss[NQ_], qssl[NQ_], qs0[NQ_], qcnt[NQ_];

    const int t    = threadIdx.x;
    const int lane = t & 63;
    const int wv   = t >> 6;        // wave 0..3 computes rows wv*32..+31
    const int fr   = lane & 15;
    const int fq   = lane >> 4;
    const int row0 = blockIdx.x * TM;

    if (t < NQ_) {
        qn_sh[t]  = ws[WS_QN + t];
        qsc_sh[t] = score[BS_ + t];
        qmn[t] = INFINITY; qmx[t] = -INFINITY;
        qss[t] = 0.f; qssl[t] = 0.f; qs0[t] = 0.f; qcnt[t] = 0.f;
        int rg = row0 + t;
        lab_s[t] = (rg < NCOL_) ? ((rg < NVL_) ? itm[rg] : expl[rg - NVL_]) : 0.f;
    }
    const float b0 = bvec[0], b1 = bvec[1];
    const float* zb = ws + WS_ZERO;

    // per-lane A row pointers (frag layout: row = wv*32 + m*16 + fr, k-slice = fq*8)
    const float* ap[2];
#pragma unroll
    for (int m = 0; m < 2; ++m) {
        const int rg = row0 + wv * 32 + m * 16 + fr;
        const float* base = (rg < NVL_)  ? (vl + (size_t)rg * D_)
                          : (rg < NCOL_) ? (queue + (size_t)(rg - NVL_) * D_)
                                         : zb;
        ap[m] = base + fq * 8;
    }
    const char* qbf     = (const char*)(ws + WS_QBF);
    const int  bsrc_off = wv * 1024 + lane * 16;

    float ssr[2] = {0.f, 0.f}, z0r[2] = {0.f, 0.f}, z1r[2] = {0.f, 0.f};
    f32x4 acc[2][8];
#pragma unroll
    for (int m = 0; m < 2; ++m)
#pragma unroll
        for (int n = 0; n < 8; ++n) acc[m][n] = (f32x4){0.f, 0.f, 0.f, 0.f};

    float4 aA[2][2][2], aB[2][2][2];   // [step-in-pair][m][half]

#define LOAD_A2(DST, SB) {                                                     \
    _Pragma("unroll")                                                          \
    for (int st_ = 0; st_ < 2; ++st_) {                                        \
        _Pragma("unroll")                                                      \
        for (int m_ = 0; m_ < 2; ++m_) {                                       \
            const float* p_ = ap[m_] + ((SB) + st_) * BK;                      \
            DST[st_][m_][0] = *(const float4*)(p_);                            \
            DST[st_][m_][1] = *(const float4*)(p_ + 4);                        \
        }                                                                      \
    } }

#define STAGE_B(TILE, BUF) {                                                   \
    char* lb_ = (char*)&Bs[BUF][0][0];                                         \
    _Pragma("unroll")                                                          \
    for (int i_ = 0; i_ < 2; ++i_)                                             \
        __builtin_amdgcn_global_load_lds(                                      \
            (const __attribute__((address_space(1))) void*)                    \
                (qbf + (size_t)(TILE) * 8192 + i_ * 4096 + bsrc_off),          \
            (__attribute__((address_space(3))) void*)(lb_ + wv * 1024 + i_ * 4096), \
            16, 0, 0); }

#define COMPUTE1(AR, SLOT, SB, BUF) {                                          \
    bf16x8 af_[2];                                                             \
    const float* wp_ = W + 2 * ((SB) * BK + fq * 8);                           \
    const float4 w0_ = *(const float4*)(wp_);                                  \
    const float4 w1_ = *(const float4*)(wp_ + 4);                              \
    const float4 w2_ = *(const float4*)(wp_ + 8);                              \
    const float4 w3_ = *(const float4*)(wp_ + 12);                             \
    _Pragma("unroll")                                                          \
    for (int m_ = 0; m_ < 2; ++m_) {                                           \
        const float4 v0_ = AR[SLOT][m_][0];                                    \
        const float4 v1_ = AR[SLOT][m_][1];                                    \
        ssr[m_] += v0_.x*v0_.x + v0_.y*v0_.y + v0_.z*v0_.z + v0_.w*v0_.w       \
                 + v1_.x*v1_.x + v1_.y*v1_.y + v1_.z*v1_.z + v1_.w*v1_.w;      \
        z0r[m_] += v0_.x*w0_.x + v0_.y*w0_.z + v0_.z*w1_.x + v0_.w*w1_.z       \
                 + v1_.x*w2_.x + v1_.y*w2_.z + v1_.z*w3_.x + v1_.w*w3_.z;      \
        z1r[m_] += v0_.x*w0_.y + v0_.y*w0_.w + v0_.z*w1_.y + v0_.w*w1_.w       \
                 + v1_.x*w2_.y + v1_.y*w2_.w + v1_.z*w3_.y + v1_.w*w3_.w;      \
        union { unsigned u[4]; bf16x8 v; } cv_;                                \
        cv_.u[0] = pk2bf(v0_.x, v0_.y); cv_.u[1] = pk2bf(v0_.z, v0_.w);        \
        cv_.u[2] = pk2bf(v1_.x, v1_.y); cv_.u[3] = pk2bf(v1_.z, v1_.w);        \
        af_[m_] = cv_.v;                                                       \
    }                                                                          \
    const char* bb_ = (const char*)&Bs[BUF][0][0];                             \
    _Pragma("unroll")                                                          \
    for (int n_ = 0; n_ < 8; ++n_) {                                           \
        const int rb_ = n_ * 16 + fr;                                          \
        bf16x8 bv_ = *(const bf16x8*)(bb_ + rb_ * 64 + 16 * (fq ^ ((rb_ >> 1) & 3))); \
        acc[0][n_] = __builtin_amdgcn_mfma_f32_16x16x32_bf16(af_[0], bv_, acc[0][n_], 0, 0, 0); \
        acc[1][n_] = __builtin_amdgcn_mfma_f32_16x16x32_bf16(af_[1], bv_, acc[1][n_], 0, 0, 0); \
    } }

    // prologue: tiles 0,1 -> bufs 0,1; A steps 0,1
    STAGE_B(0, 0); STAGE_B(1, 1);
    LOAD_A2(aA, 0);
    __syncthreads();

#pragma unroll 1
    for (int P = 0; P < 12; P += 2) {
        // body A (pair P, even): compute steps 2P,2P+1 from bufs 0,1 + aA
        STAGE_B(2 * P + 2, 2); STAGE_B(2 * P + 3, 3);      // tiles for pair P+1
        LOAD_A2(aB, 2 * P + 2);
        COMPUTE1(aA, 0, 2 * P,     0);
        COMPUTE1(aA, 1, 2 * P + 1, 1);
        __syncthreads();
        // body B (pair P+1, odd): compute steps 2P+2,2P+3 from bufs 2,3 + aB
        if (P < 10) {
            STAGE_B(2 * P + 4, 0); STAGE_B(2 * P + 5, 1);  // tiles for pair P+2
            LOAD_A2(aA, 2 * P + 4);
        }
        COMPUTE1(aB, 0, 2 * P + 2, 2);
        COMPUTE1(aB, 1, 2 * P + 3, 3);
        __syncthreads();
    }
#undef LOAD_A2
#undef STAGE_B
#undef COMPUTE1

    // per-pre-row stats: reduce over the 4 fq lanes sharing a row
#pragma unroll
    for (int m = 0; m < 2; ++m) {
        ssr[m] += __shfl_xor(ssr[m], 16); ssr[m] += __shfl_xor(ssr[m], 32);
        z0r[m] += __shfl_xor(z0r[m], 16); z0r[m] += __shfl_xor(z0r[m], 32);
        z1r[m] += __shfl_xor(z1r[m], 16); z1r[m] += __shfl_xor(z1r[m], 32);
        if (fq == 0) {
            const int r  = wv * 32 + m * 16 + fr;
            const int rg = row0 + r;
            rn_s[r] = sqrtf(ssr[m]);
            float sc;
            if (rg < NVL_) sc = score[rg];
            else { float z = (z1r[m] + b1) - (z0r[m] + b0); sc = 1.f / (1.f + expf(-z)); }
            rsc_s[r] = sc;
        }
    }
    __syncthreads();

    // epilogue: per-query online reductions over this block's TM pre-rows
#pragma unroll
    for (int n = 0; n < 8; ++n) {
        const int   c   = n * 16 + fr;
        const float qn  = qn_sh[c];
        const float qsc = qsc_sh[c];
        float mn = INFINITY, mx = -INFINITY, sss = 0.f, ssl = 0.f, s0 = 0.f, cnt = 0.f;
#pragma unroll
        for (int m = 0; m < 2; ++m) {
#pragma unroll
            for (int j = 0; j < 4; ++j) {
                const int r  = wv * 32 + m * 16 + fq * 4 + j;   // C row = pre row
                const int rg = row0 + r;
                const float d    = acc[m][n][j];
                const float cosv = d / fmaxf(rn_s[r] * qn, EPS_);
                float dd = rsc_s[r] - qsc; dd *= dd;
                const float sim   = cosv * (1.f - dd);
                const bool  sel   = (cosv >= THR_);
                const float sim_m = sel ? sim : -1.f;
                const bool  valid = (rg < NCOL_);
                mn = fminf(mn, valid ? sim_m : INFINITY);
                mx = fmaxf(mx, valid ? sim_m : -INFINITY);
                sss += sim_m + 1.f;                 // OOB rows: cos=0 -> exactly 0
                ssl += (sim_m + 1.f) * lab_s[r];
                if (sel) { s0 += sim; cnt += 1.f; }
            }
        }
        mn  = fminf(mn, __shfl_xor(mn, 16)); mn  = fminf(mn, __shfl_xor(mn, 32));
        mx  = fmaxf(mx, __shfl_xor(mx, 16)); mx  = fmaxf(mx, __shfl_xor(mx, 32));
        sss += __shfl_xor(sss, 16); sss += __shfl_xor(sss, 32);
        ssl += __shfl_xor(ssl, 16); ssl += __shfl_xor(ssl, 32);
        s0  += __shfl_xor(s0, 16);  s0  += __shfl_xor(s0, 32);
        cnt += __shfl_xor(cnt, 16); cnt += __shfl_xor(cnt, 32);
        if (fq == 0) {
            atomicMinF(&qmn[c], mn);
            atomicMaxF(&qmx[c], mx);
            atomicAdd(&qss[c],  sss);
            atomicAdd(&qssl[c], ssl);
            atomicAdd(&qs0[c],  s0);
            atomicAdd(&qcnt[c], cnt);
        }
    }
    __syncthreads();
    if (t < NQ_) {
        atomicMinF(ws + WS_MN + t, qmn[t]);
        atomicMaxF(ws + WS_MX + t, qmx[t]);
        atomicAdd(ws + WS_SS + t,  qss[t]);
        atomicAdd(ws + WS_SSL + t, qssl[t]);
        atomicAdd(ws + WS_S0 + t,  qs0[t]);
        atomicAdd(ws + WS_CNT + t, qcnt[t]);
    }
}

// ---------------- kernel 3: finalize outputs ----------------
__global__ void lpe_final(float* out, const float* ws) {
    int t = threadIdx.x;
    if (t < BS_) {
        out[t] = 1.f;            // exp_itm_label[:64]
        out[192 + t] = 1.f;      // exp_wo_alter_label[:64]
        out[385 + t] = 0.f;      // weights[:64]
    }
    if (t == 0) out[384] = 1.0f; // gamma = 131264/131264
    if (t >= BS_ && t < NVL_) {
        int i = t - BS_;
        float mn   = ws[WS_MN + i],  mx   = ws[WS_MX + i];
        float ssP  = ws[WS_SS + i],  sslP = ws[WS_SSL + i];
        float s0   = ws[WS_S0 + i],  cnt  = ws[WS_CNT + i];
        float Sl   = ws[WS_SL];
        float denomA = mx - mn + 1e-8f;
        float shift  = mn + 1.f;            // == 0 when min is the -1 sentinel
        float sumd = (ssP - (float)NCOL_ * shift) / denomA;
        float num  = (sslP - shift * Sl) / denomA;
        float wo   = num / (sumd + 1e-8f);
        float alt  = fmaxf(wo, 0.f);
        float w    = (cnt != 0.f) ? s0 / fmaxf(cnt, 1.f) : 0.f;
        float wt   = fmaxf(w - THR_, 0.f) / (1.f - THR_);
        out[BS_ + i] = alt;          // exp_itm_label[64:]
        out[192 + BS_ + i] = wo;     // exp_wo_alter_label[64:]
        out[385 + BS_ + i] = wt;     // weights[64:]
    }
}

extern "C" void kernel_launch(void* const* d_in, const int* in_sizes, int n_in,
                              void* d_out, int out_size, void* d_ws, size_t ws_size,
                              hipStream_t stream) {
    const float* vl    = (const float*)d_in[0];
    const float* score = (const float*)d_in[1];
    const float* itm   = (const float*)d_in[2];
    const float* queue = (const float*)d_in[3];
    const float* expl  = (const float*)d_in[4];
    const float* W     = (const float*)d_in[5];
    const float* b     = (const float*)d_in[6];
    float* out = (float*)d_out;
    float* ws  = (float*)d_ws;

    lpe_init<<<1, 256, 0, stream>>>(ws);
    lpe_prep<<<NQ_ + 256, 256, 0, stream>>>(vl, itm, expl, ws);
    const int nblk = (NCOL_ + TM - 1) / TM;   // 1026
    lpe_main<<<nblk, 256, 0, stream>>>(vl, score, itm, queue, expl, W, b, ws);
    lpe_final<<<1, 256, 0, stream>>>(out, ws);
}

// Round 8
// 168.091 us; speedup vs baseline: 1.7730x; 1.7730x over previous
//
#include <hip/hip_runtime.h>
#include <math.h>

namespace {
constexpr int   BS_   = 64;
constexpr int   D_    = 768;
constexpr int   NVL_  = 192;            // 3*BS rows of vl_embeddings
constexpr int   NQ_   = 128;            // query rows (vl[64:])
constexpr int   CAP_  = 131072;
constexpr int   NCOL_ = NVL_ + CAP_;    // 131264 (the PRE dimension)
constexpr float THR_  = 0.5f;
constexpr float EPS_  = 1e-8f;

// workspace float offsets
constexpr int WS_QN   = 0;    // 128 query norms
constexpr int WS_SL   = 128;  // 1   global label sum
constexpr int WS_MN   = 160;  // 128 per-query min(sim_m)
constexpr int WS_MX   = 288;  // 128 per-query max(sim_m)
constexpr int WS_SS   = 416;  // 128 per-query sum(sim_m + 1)
constexpr int WS_SSL  = 544;  // 128 per-query sum((sim_m + 1)*label)
constexpr int WS_S0   = 672;  // 128 per-query sum(sim where selected)
constexpr int WS_CNT  = 800;  // 128 per-query count(selected)
constexpr int WS_ZERO = 1024; // 768 zero floats (safe OOB source)
constexpr int WS_QBF  = 2048; // 49152 floats: q bf16, 24 tiles of 8192 B (swizzled LDS image)

constexpr int TM    = 128;    // pre-rows per block
constexpr int BK    = 32;     // k per step
constexpr int NSTEP = D_ / BK;   // 24
}

using bf16x8 = __attribute__((ext_vector_type(8))) short;
using f32x4  = __attribute__((ext_vector_type(4))) float;

__device__ inline void atomicMinF(float* addr, float v) {
    if (v >= 0.f) atomicMin((int*)addr, __float_as_int(v));
    else          atomicMax((unsigned int*)addr, __float_as_uint(v));
}
__device__ inline void atomicMaxF(float* addr, float v) {
    if (v >= 0.f) atomicMax((int*)addr, __float_as_int(v));
    else          atomicMin((unsigned int*)addr, __float_as_uint(v));
}
// pack two f32 -> two bf16 (RNE) in one u32
__device__ inline unsigned pk2bf(float a, float b) {
    unsigned ua = __float_as_uint(a), ub = __float_as_uint(b);
    ua += 0x7fffu + ((ua >> 16) & 1u);
    ub += 0x7fffu + ((ub >> 16) & 1u);
    return (ua >> 16) | (ub & 0xffff0000u);
}

// ---------------- kernel 0: init accumulators + zero pad buffer ----------------
__global__ void lpe_init(float* ws) {
    int t = threadIdx.x;
    if (t < NQ_) {
        ws[WS_MN + t]  = INFINITY;
        ws[WS_MX + t]  = -INFINITY;
        ws[WS_SS + t]  = 0.f;
        ws[WS_SSL + t] = 0.f;
        ws[WS_S0 + t]  = 0.f;
        ws[WS_CNT + t] = 0.f;
    }
    if (t == 0) ws[WS_SL] = 0.f;
    for (int i = t; i < D_; i += 256) ws[WS_ZERO + i] = 0.f;
}

// ---------------- kernel 1: query norms + q bf16 image + global label sum ----------------
__global__ void lpe_prep(const float* __restrict__ vl,
                         const float* __restrict__ itm,
                         const float* __restrict__ expl,
                         float* ws) {
    __shared__ float red[256];
    int b = blockIdx.x, t = threadIdx.x;
    if (b < NQ_) {
        const float* row = vl + (size_t)(BS_ + b) * D_;
        float s = 0.f;
        for (int k = t; k < D_; k += 256) { float v = row[k]; s += v * v; }
        red[t] = s; __syncthreads();
        for (int o = 128; o > 0; o >>= 1) { if (t < o) red[t] += red[t + o]; __syncthreads(); }
        if (t == 0) ws[WS_QN + b] = sqrtf(red[0]);
        // swizzled bf16 image: tile s (8192 B) = [row][64 B], byte = (kk*2) ^ ((row>>1 & 3)<<4)
        unsigned* qbf = (unsigned*)(ws + WS_QBF);
        const int sw = ((b >> 1) & 3) << 4;
        for (int k2 = t; k2 < 384; k2 += 256) {
            const int k = 2 * k2, tile = k >> 5, kk = k & 31;
            const unsigned val = pk2bf(row[k], row[k + 1]);
            const int byte = tile * 8192 + b * 64 + (((kk * 2) ^ sw) & 63);
            qbf[byte >> 2] = val;
        }
    } else {
        int idx = (b - NQ_) * 256 + t;
        float s = 0.f;
        for (int j = idx; j < NCOL_; j += 256 * 256)
            s += (j < NVL_) ? itm[j] : expl[j - NVL_];
        red[t] = s; __syncthreads();
        for (int o = 128; o > 0; o >>= 1) { if (t < o) red[t] += red[t + o]; __syncthreads(); }
        if (t == 0) atomicAdd(ws + WS_SL, red[0]);
    }
}

// ---------------- kernel 2: barrier-free main loop, wave-private B dbuf, counted vmcnt ----
// M = pre rows (128/block), N = 128 queries, K = 768, BK = 32.
__global__ __launch_bounds__(256, 2) void lpe_main(
        const float* __restrict__ vl, const float* __restrict__ score,
        const float* __restrict__ itm, const float* __restrict__ queue,
        const float* __restrict__ expl, const float* __restrict__ W,
        const float* __restrict__ bvec, float* ws) {
    __shared__ __align__(16) short Bs[4][2][NQ_][BK];  // per-wave private dbuf, 64 KB
    __shared__ __align__(16) float Wl[2 * D_];         // W copy, 6 KB
    __shared__ float rn_s[TM], rsc_s[TM], lab_s[TM];
    __shared__ float qn_sh[NQ_], qsc_sh[NQ_];
    __shared__ float qmn[NQ_], qmx[NQ_], qss[NQ_], qssl[NQ_], qs0[NQ_], qcnt[NQ_];

    const int t    = threadIdx.x;
    const int lane = t & 63;
    const int wv   = t >> 6;        // wave 0..3 computes rows wv*32..+31
    const int fr   = lane & 15;
    const int fq   = lane >> 4;
    const int row0 = blockIdx.x * TM;

    if (t < NQ_) {
        qn_sh[t]  = ws[WS_QN + t];
        qsc_sh[t] = score[BS_ + t];
        qmn[t] = INFINITY; qmx[t] = -INFINITY;
        qss[t] = 0.f; qssl[t] = 0.f; qs0[t] = 0.f; qcnt[t] = 0.f;
        int rg = row0 + t;
        lab_s[t] = (rg < NCOL_) ? ((rg < NVL_) ? itm[rg] : expl[rg - NVL_]) : 0.f;
    }
    for (int i = t; i < 2 * D_; i += 256) Wl[i] = W[i];
    const float b0 = bvec[0], b1 = bvec[1];
    const float* zb = ws + WS_ZERO;

    // per-lane A row pointers (frag: row = wv*32 + m*16 + fr, k-slice = fq*8)
    const float* ap[2];
#pragma unroll
    for (int m = 0; m < 2; ++m) {
        const int rg = row0 + wv * 32 + m * 16 + fr;
        const float* base = (rg < NVL_)  ? (vl + (size_t)rg * D_)
                          : (rg < NCOL_) ? (queue + (size_t)(rg - NVL_) * D_)
                                         : zb;
        ap[m] = base + fq * 8;
    }
    const char* qbf = (const char*)(ws + WS_QBF);

    float ssr[2] = {0.f, 0.f}, z0r[2] = {0.f, 0.f}, z1r[2] = {0.f, 0.f};
    f32x4 acc[2][8];
#pragma unroll
    for (int m = 0; m < 2; ++m)
#pragma unroll
        for (int n = 0; n < 8; ++n) acc[m][n] = (f32x4){0.f, 0.f, 0.f, 0.f};

    float4 aA[2][2], aB[2][2];   // [m][half] A prefetch slots (static indexing only)

    // each wave copies the WHOLE 8 KB tile into its private buffer: 8 vmem insts
#define STAGE_B(TILE, BUF) {                                                   \
    char* lb_ = (char*)&Bs[wv][BUF][0][0];                                     \
    const char* src_ = qbf + (size_t)(TILE) * 8192;                            \
    _Pragma("unroll")                                                          \
    for (int i_ = 0; i_ < 8; ++i_)                                             \
        __builtin_amdgcn_global_load_lds(                                      \
            (const __attribute__((address_space(1))) void*)(src_ + i_ * 1024 + lane * 16), \
            (__attribute__((address_space(3))) void*)(lb_ + i_ * 1024),        \
            16, 0, 0); }

    // 4 vmem insts
#define LOAD_A(DST, S) {                                                       \
    _Pragma("unroll")                                                          \
    for (int m_ = 0; m_ < 2; ++m_) {                                           \
        const float* p_ = ap[m_] + (S) * BK;                                   \
        DST[m_][0] = *(const float4*)(p_);                                     \
        DST[m_][1] = *(const float4*)(p_ + 4);                                 \
    } }

#define COMPUTE(SB, AR, BUF) {                                                 \
    bf16x8 af_[2];                                                             \
    const float* wp_ = &Wl[(SB) * 64 + fq * 16];                               \
    const float4 w0_ = *(const float4*)(wp_);                                  \
    const float4 w1_ = *(const float4*)(wp_ + 4);                              \
    const float4 w2_ = *(const float4*)(wp_ + 8);                              \
    const float4 w3_ = *(const float4*)(wp_ + 12);                             \
    _Pragma("unroll")                                                          \
    for (int m_ = 0; m_ < 2; ++m_) {                                           \
        const float4 v0_ = AR[m_][0];                                          \
        const float4 v1_ = AR[m_][1];                                          \
        ssr[m_] += v0_.x*v0_.x + v0_.y*v0_.y + v0_.z*v0_.z + v0_.w*v0_.w       \
                 + v1_.x*v1_.x + v1_.y*v1_.y + v1_.z*v1_.z + v1_.w*v1_.w;      \
        z0r[m_] += v0_.x*w0_.x + v0_.y*w0_.z + v0_.z*w1_.x + v0_.w*w1_.z       \
                 + v1_.x*w2_.x + v1_.y*w2_.z + v1_.z*w3_.x + v1_.w*w3_.z;      \
        z1r[m_] += v0_.x*w0_.y + v0_.y*w0_.w + v0_.z*w1_.y + v0_.w*w1_.w       \
                 + v1_.x*w2_.y + v1_.y*w2_.w + v1_.z*w3_.y + v1_.w*w3_.w;      \
        union { unsigned u[4]; bf16x8 v; } cv_;                                \
        cv_.u[0] = pk2bf(v0_.x, v0_.y); cv_.u[1] = pk2bf(v0_.z, v0_.w);        \
        cv_.u[2] = pk2bf(v1_.x, v1_.y); cv_.u[3] = pk2bf(v1_.z, v1_.w);        \
        af_[m_] = cv_.v;                                                       \
    }                                                                          \
    const char* bb_ = (const char*)&Bs[wv][BUF][0][0];                         \
    _Pragma("unroll")                                                          \
    for (int n_ = 0; n_ < 8; ++n_) {                                           \
        const int rb_ = n_ * 16 + fr;                                          \
        bf16x8 bv_ = *(const bf16x8*)(bb_ + rb_ * 64 + 16 * (fq ^ ((rb_ >> 1) & 3))); \
        acc[0][n_] = __builtin_amdgcn_mfma_f32_16x16x32_bf16(af_[0], bv_, acc[0][n_], 0, 0, 0); \
        acc[1][n_] = __builtin_amdgcn_mfma_f32_16x16x32_bf16(af_[1], bv_, acc[1][n_], 0, 0, 0); \
    } }

    // prologue: B(0) -> buf0; A(0) -> aA; A(1) -> aB; barrier also publishes init/W
    STAGE_B(0, 0);
    LOAD_A(aA, 0);
    LOAD_A(aB, 1);
    __syncthreads();

    // main loop: NO barriers. Each half issues exactly 12 vmem insts;
    // vmcnt(4) leaves only the newest A-prefetch outstanding => B(s),A(s) complete.
#pragma unroll 1
    for (int s = 0; s < NSTEP; s += 2) {
        const int c2 = (s + 2 < NSTEP) ? s + 2 : NSTEP - 1;
        const int c3 = (s + 3 < NSTEP) ? s + 3 : NSTEP - 1;
        asm volatile("s_waitcnt vmcnt(4)" ::: "memory");
        COMPUTE(s, aA, 0);
        STAGE_B(s + 1, 1);            // s+1 <= 23 always (s even, s <= 22)
        LOAD_A(aA, c2);
        asm volatile("s_waitcnt vmcnt(4)" ::: "memory");
        COMPUTE(s + 1, aB, 1);
        STAGE_B(c2, 0);
        LOAD_A(aB, c3);
    }
#undef STAGE_B
#undef LOAD_A
#undef COMPUTE

    // per-pre-row stats: reduce over the 4 fq lanes sharing a row (same wave)
#pragma unroll
    for (int m = 0; m < 2; ++m) {
        ssr[m] += __shfl_xor(ssr[m], 16); ssr[m] += __shfl_xor(ssr[m], 32);
        z0r[m] += __shfl_xor(z0r[m], 16); z0r[m] += __shfl_xor(z0r[m], 32);
        z1r[m] += __shfl_xor(z1r[m], 16); z1r[m] += __shfl_xor(z1r[m], 32);
        if (fq == 0) {
            const int r  = wv * 32 + m * 16 + fr;
            const int rg = row0 + r;
            rn_s[r] = sqrtf(ssr[m]);
            float sc;
            if (rg < NVL_) sc = score[rg];
            else { float z = (z1r[m] + b1) - (z0r[m] + b0); sc = 1.f / (1.f + expf(-z)); }
            rsc_s[r] = sc;
        }
    }

    // epilogue: per-query online reductions over this block's TM pre-rows
    // (rn_s/rsc_s are own-wave-written; lab_s/qn_sh/qsc_sh published by barrier above)
#pragma unroll
    for (int n = 0; n < 8; ++n) {
        const int   c   = n * 16 + fr;
        const float qn  = qn_sh[c];
        const float qsc = qsc_sh[c];
        float mn = INFINITY, mx = -INFINITY, sss = 0.f, ssl = 0.f, s0 = 0.f, cnt = 0.f;
#pragma unroll
        for (int m = 0; m < 2; ++m) {
#pragma unroll
            for (int j = 0; j < 4; ++j) {
                const int r  = wv * 32 + m * 16 + fq * 4 + j;   // C row = pre row
                const int rg = row0 + r;
                const float d    = acc[m][n][j];
                const float cosv = d / fmaxf(rn_s[r] * qn, EPS_);
                float dd = rsc_s[r] - qsc; dd *= dd;
                const float sim   = cosv * (1.f - dd);
                const bool  sel   = (cosv >= THR_);
                const float sim_m = sel ? sim : -1.f;
                const bool  valid = (rg < NCOL_);
                mn = fminf(mn, valid ? sim_m : INFINITY);
                mx = fmaxf(mx, valid ? sim_m : -INFINITY);
                sss += sim_m + 1.f;                 // OOB rows: cos=0 -> exactly 0
                ssl += (sim_m + 1.f) * lab_s[r];
                if (sel) { s0 += sim; cnt += 1.f; }
            }
        }
        mn  = fminf(mn, __shfl_xor(mn, 16)); mn  = fminf(mn, __shfl_xor(mn, 32));
        mx  = fmaxf(mx, __shfl_xor(mx, 16)); mx  = fmaxf(mx, __shfl_xor(mx, 32));
        sss += __shfl_xor(sss, 16); sss += __shfl_xor(sss, 32);
        ssl += __shfl_xor(ssl, 16); ssl += __shfl_xor(ssl, 32);
        s0  += __shfl_xor(s0, 16);  s0  += __shfl_xor(s0, 32);
        cnt += __shfl_xor(cnt, 16); cnt += __shfl_xor(cnt, 32);
        if (fq == 0) {
            atomicMinF(&qmn[c], mn);
            atomicMaxF(&qmx[c], mx);
            atomicAdd(&qss[c],  sss);
            atomicAdd(&qssl[c], ssl);
            atomicAdd(&qs0[c],  s0);
            atomicAdd(&qcnt[c], cnt);
        }
    }
    __syncthreads();
    if (t < NQ_) {
        atomicMinF(ws + WS_MN + t, qmn[t]);
        atomicMaxF(ws + WS_MX + t, qmx[t]);
        atomicAdd(ws + WS_SS + t,  qss[t]);
        atomicAdd(ws + WS_SSL + t, qssl[t]);
        atomicAdd(ws + WS_S0 + t,  qs0[t]);
        atomicAdd(ws + WS_CNT + t, qcnt[t]);
    }
}

// ---------------- kernel 3: finalize outputs ----------------
__global__ void lpe_final(float* out, const float* ws) {
    int t = threadIdx.x;
    if (t < BS_) {
        out[t] = 1.f;            // exp_itm_label[:64]
        out[192 + t] = 1.f;      // exp_wo_alter_label[:64]
        out[385 + t] = 0.f;      // weights[:64]
    }
    if (t == 0) out[384] = 1.0f; // gamma = 131264/131264
    if (t >= BS_ && t < NVL_) {
        int i = t - BS_;
        float mn   = ws[WS_MN + i],  mx   = ws[WS_MX + i];
        float ssP  = ws[WS_SS + i],  sslP = ws[WS_SSL + i];
        float s0   = ws[WS_S0 + i],  cnt  = ws[WS_CNT + i];
        float Sl   = ws[WS_SL];
        float denomA = mx - mn + 1e-8f;
        float shift  = mn + 1.f;            // == 0 when min is the -1 sentinel
        float sumd = (ssP - (float)NCOL_ * shift) / denomA;
        float num  = (sslP - shift * Sl) / denomA;
        float wo   = num / (sumd + 1e-8f);
        float alt  = fmaxf(wo, 0.f);
        float w    = (cnt != 0.f) ? s0 / fmaxf(cnt, 1.f) : 0.f;
        float wt   = fmaxf(w - THR_, 0.f) / (1.f - THR_);
        out[BS_ + i] = alt;          // exp_itm_label[64:]
        out[192 + BS_ + i] = wo;     // exp_wo_alter_label[64:]
        out[385 + BS_ + i] = wt;     // weights[64:]
    }
}

extern "C" void kernel_launch(void* const* d_in, const int* in_sizes, int n_in,
                              void* d_out, int out_size, void* d_ws, size_t ws_size,
                              hipStream_t stream) {
    const float* vl    = (const float*)d_in[0];
    const float* score = (const float*)d_in[1];
    const float* itm   = (const float*)d_in[2];
    const float* queue = (const float*)d_in[3];
    const float* expl  = (const float*)d_in[4];
    const float* W     = (const float*)d_in[5];
    const float* b     = (const float*)d_in[6];
    float* out = (float*)d_out;
    float* ws  = (float*)d_ws;

    lpe_init<<<1, 256, 0, stream>>>(ws);
    lpe_prep<<<NQ_ + 256, 256, 0, stream>>>(vl, itm, expl, ws);
    const int nblk = (NCOL_ + TM - 1) / TM;   // 1026
    lpe_main<<<nblk, 256, 0, stream>>>(vl, score, itm, queue, expl, W, b, ws);
    lpe_final<<<1, 256, 0, stream>>>(out, ws);
}

// Round 9
// 143.678 us; speedup vs baseline: 2.0742x; 1.1699x over previous
//
#include <hip/hip_runtime.h>
#include <math.h>

namespace {
constexpr int   BS_   = 64;
constexpr int   D_    = 768;
constexpr int   NVL_  = 192;            // 3*BS rows of vl_embeddings
constexpr int   NQ_   = 128;            // query rows (vl[64:])
constexpr int   CAP_  = 131072;
constexpr int   NCOL_ = NVL_ + CAP_;    // 131264 (the PRE dimension)
constexpr float THR_  = 0.5f;
constexpr float EPS_  = 1e-8f;

// workspace float offsets
constexpr int WS_QN   = 0;    // 128 query norms
constexpr int WS_SL   = 128;  // 1   global label sum
constexpr int WS_MN   = 160;  // 128 per-query min(sim_m)
constexpr int WS_MX   = 288;  // 128 per-query max(sim_m)
constexpr int WS_SS   = 416;  // 128 per-query sum(sim_m + 1)
constexpr int WS_SSL  = 544;  // 128 per-query sum((sim_m + 1)*label)
constexpr int WS_S0   = 672;  // 128 per-query sum(sim where selected)
constexpr int WS_CNT  = 800;  // 128 per-query count(selected)
constexpr int WS_ZERO = 1024; // 768 zero floats (safe OOB source)
constexpr int WS_QBF  = 2048; // 49152 floats: q bf16, 24 tiles of 8192 B (swizzled LDS image)

constexpr int TM    = 128;    // pre-rows per block
constexpr int BK    = 32;     // k per step
constexpr int NSTEP = D_ / BK;   // 24
}

using bf16x8 = __attribute__((ext_vector_type(8))) short;
using f32x4  = __attribute__((ext_vector_type(4))) float;

__device__ inline void atomicMinF(float* addr, float v) {
    if (v >= 0.f) atomicMin((int*)addr, __float_as_int(v));
    else          atomicMax((unsigned int*)addr, __float_as_uint(v));
}
__device__ inline void atomicMaxF(float* addr, float v) {
    if (v >= 0.f) atomicMax((int*)addr, __float_as_int(v));
    else          atomicMin((unsigned int*)addr, __float_as_uint(v));
}
// pack two f32 -> two bf16 (RNE) in one u32
__device__ inline unsigned pk2bf(float a, float b) {
    unsigned ua = __float_as_uint(a), ub = __float_as_uint(b);
    ua += 0x7fffu + ((ua >> 16) & 1u);
    ub += 0x7fffu + ((ub >> 16) & 1u);
    return (ua >> 16) | (ub & 0xffff0000u);
}

// ---------------- kernel 0: init accumulators + zero pad buffer ----------------
__global__ void lpe_init(float* ws) {
    int t = threadIdx.x;
    if (t < NQ_) {
        ws[WS_MN + t]  = INFINITY;
        ws[WS_MX + t]  = -INFINITY;
        ws[WS_SS + t]  = 0.f;
        ws[WS_SSL + t] = 0.f;
        ws[WS_S0 + t]  = 0.f;
        ws[WS_CNT + t] = 0.f;
    }
    if (t == 0) ws[WS_SL] = 0.f;
    for (int i = t; i < D_; i += 256) ws[WS_ZERO + i] = 0.f;
}

// ---------------- kernel 1: query norms + q bf16 image + global label sum ----------------
__global__ void lpe_prep(const float* __restrict__ vl,
                         const float* __restrict__ itm,
                         const float* __restrict__ expl,
                         float* ws) {
    __shared__ float red[256];
    int b = blockIdx.x, t = threadIdx.x;
    if (b < NQ_) {
        const float* row = vl + (size_t)(BS_ + b) * D_;
        float s = 0.f;
        for (int k = t; k < D_; k += 256) { float v = row[k]; s += v * v; }
        red[t] = s; __syncthreads();
        for (int o = 128; o > 0; o >>= 1) { if (t < o) red[t] += red[t + o]; __syncthreads(); }
        if (t == 0) ws[WS_QN + b] = sqrtf(red[0]);
        // swizzled bf16 image: tile s (8192 B) = [row][64 B], byte = (kk*2) ^ ((row>>1 & 3)<<4)
        unsigned* qbf = (unsigned*)(ws + WS_QBF);
        const int sw = ((b >> 1) & 3) << 4;
        for (int k2 = t; k2 < 384; k2 += 256) {
            const int k = 2 * k2, tile = k >> 5, kk = k & 31;
            const unsigned val = pk2bf(row[k], row[k + 1]);
            const int byte = tile * 8192 + b * 64 + (((kk * 2) ^ sw) & 63);
            qbf[byte >> 2] = val;
        }
    } else {
        int idx = (b - NQ_) * 256 + t;
        float s = 0.f;
        for (int j = idx; j < NCOL_; j += 256 * 256)
            s += (j < NVL_) ? itm[j] : expl[j - NVL_];
        red[t] = s; __syncthreads();
        for (int o = 128; o > 0; o >>= 1) { if (t < o) red[t] += red[t + o]; __syncthreads(); }
        if (t == 0) atomicAdd(ws + WS_SL, red[0]);
    }
}

// ---------------- kernel 2: shared-B dbuf, raw barrier + counted vmcnt (no drain) ----
// M = pre rows (128/block), N = 128 queries, K = 768, BK = 32.
__global__ __launch_bounds__(256, 3) void lpe_main(
        const float* __restrict__ vl, const float* __restrict__ score,
        const float* __restrict__ itm, const float* __restrict__ queue,
        const float* __restrict__ expl, const float* __restrict__ W,
        const float* __restrict__ bvec, float* ws) {
    __shared__ __align__(16) short Bs[2][NQ_][BK];     // shared B dbuf, 16 KB
    __shared__ __align__(16) float Wl[2 * D_];         // W copy, 6 KB
    __shared__ float rn_s[TM], rsc_s[TM], lab_s[TM];
    __shared__ float qn_sh[NQ_], qsc_sh[NQ_];
    __shared__ float qmn[NQ_], qmx[NQ_], qss[NQ_], qssl[NQ_], qs0[NQ_], qcnt[NQ_];

    const int t    = threadIdx.x;
    const int lane = t & 63;
    const int wv   = t >> 6;        // wave 0..3 computes rows wv*32..+31
    const int fr   = lane & 15;
    const int fq   = lane >> 4;
    const int row0 = blockIdx.x * TM;

    if (t < NQ_) {
        qn_sh[t]  = ws[WS_QN + t];
        qsc_sh[t] = score[BS_ + t];
        qmn[t] = INFINITY; qmx[t] = -INFINITY;
        qss[t] = 0.f; qssl[t] = 0.f; qs0[t] = 0.f; qcnt[t] = 0.f;
        int rg = row0 + t;
        lab_s[t] = (rg < NCOL_) ? ((rg < NVL_) ? itm[rg] : expl[rg - NVL_]) : 0.f;
    }
    for (int i = t; i < 2 * D_; i += 256) Wl[i] = W[i];
    const float b0 = bvec[0], b1 = bvec[1];
    const float* zb = ws + WS_ZERO;

    // per-lane A row pointers (frag: row = wv*32 + m*16 + fr, k-slice = fq*8)
    const float* ap[2];
#pragma unroll
    for (int m = 0; m < 2; ++m) {
        const int rg = row0 + wv * 32 + m * 16 + fr;
        const float* base = (rg < NVL_)  ? (vl + (size_t)rg * D_)
                          : (rg < NCOL_) ? (queue + (size_t)(rg - NVL_) * D_)
                                         : zb;
        ap[m] = base + fq * 8;
    }
    const char* qbf = (const char*)(ws + WS_QBF);

    float ssr[2] = {0.f, 0.f}, z0r[2] = {0.f, 0.f}, z1r[2] = {0.f, 0.f};
    f32x4 acc[2][8];
#pragma unroll
    for (int m = 0; m < 2; ++m)
#pragma unroll
        for (int n = 0; n < 8; ++n) acc[m][n] = (f32x4){0.f, 0.f, 0.f, 0.f};

    float4 aA[2][2], aB[2][2];   // [m][half] A prefetch slots (static indexing only)

    // block-cooperative B staging: wave wv covers 2 KB of the 8 KB tile (2 insts)
#define STAGE_B(TILE, BUF) {                                                   \
    char* lb_ = (char*)&Bs[BUF][0][0] + wv * 2048;                             \
    const char* src_ = qbf + (size_t)(TILE) * 8192 + wv * 2048 + lane * 16;    \
    _Pragma("unroll")                                                          \
    for (int i_ = 0; i_ < 2; ++i_)                                             \
        __builtin_amdgcn_global_load_lds(                                      \
            (const __attribute__((address_space(1))) void*)(src_ + i_ * 1024), \
            (__attribute__((address_space(3))) void*)(lb_ + i_ * 1024),        \
            16, 0, 0); }

    // 4 vmem insts
#define LOAD_A(DST, S) {                                                       \
    _Pragma("unroll")                                                          \
    for (int m_ = 0; m_ < 2; ++m_) {                                           \
        const float* p_ = ap[m_] + (S) * BK;                                   \
        DST[m_][0] = *(const float4*)(p_);                                     \
        DST[m_][1] = *(const float4*)(p_ + 4);                                 \
    } }

#define COMPUTE(SB, AR, BUF) {                                                 \
    bf16x8 af_[2];                                                             \
    const float* wp_ = &Wl[(SB) * 64 + fq * 16];                               \
    const float4 w0_ = *(const float4*)(wp_);                                  \
    const float4 w1_ = *(const float4*)(wp_ + 4);                              \
    const float4 w2_ = *(const float4*)(wp_ + 8);                              \
    const float4 w3_ = *(const float4*)(wp_ + 12);                             \
    _Pragma("unroll")                                                          \
    for (int m_ = 0; m_ < 2; ++m_) {                                           \
        const float4 v0_ = AR[m_][0];                                          \
        const float4 v1_ = AR[m_][1];                                          \
        ssr[m_] += v0_.x*v0_.x + v0_.y*v0_.y + v0_.z*v0_.z + v0_.w*v0_.w       \
                 + v1_.x*v1_.x + v1_.y*v1_.y + v1_.z*v1_.z + v1_.w*v1_.w;      \
        z0r[m_] += v0_.x*w0_.x + v0_.y*w0_.z + v0_.z*w1_.x + v0_.w*w1_.z       \
                 + v1_.x*w2_.x + v1_.y*w2_.z + v1_.z*w3_.x + v1_.w*w3_.z;      \
        z1r[m_] += v0_.x*w0_.y + v0_.y*w0_.w + v0_.z*w1_.y + v0_.w*w1_.w       \
                 + v1_.x*w2_.y + v1_.y*w2_.w + v1_.z*w3_.y + v1_.w*w3_.w;      \
        union { unsigned u[4]; bf16x8 v; } cv_;                                \
        cv_.u[0] = pk2bf(v0_.x, v0_.y); cv_.u[1] = pk2bf(v0_.z, v0_.w);        \
        cv_.u[2] = pk2bf(v1_.x, v1_.y); cv_.u[3] = pk2bf(v1_.z, v1_.w);        \
        af_[m_] = cv_.v;                                                       \
    }                                                                          \
    const char* bb_ = (const char*)&Bs[BUF][0][0];                             \
    _Pragma("unroll")                                                          \
    for (int n_ = 0; n_ < 8; ++n_) {                                           \
        const int rb_ = n_ * 16 + fr;                                          \
        bf16x8 bv_ = *(const bf16x8*)(bb_ + rb_ * 64 + 16 * (fq ^ ((rb_ >> 1) & 3))); \
        acc[0][n_] = __builtin_amdgcn_mfma_f32_16x16x32_bf16(af_[0], bv_, acc[0][n_], 0, 0, 0); \
        acc[1][n_] = __builtin_amdgcn_mfma_f32_16x16x32_bf16(af_[1], bv_, acc[1][n_], 0, 0, 0); \
    } }

    // prologue: B(0) -> buf0; A(0) -> aA; A(1) -> aB; full drain publishes init/W/B0
    STAGE_B(0, 0);
    LOAD_A(aA, 0);
    LOAD_A(aB, 1);
    __syncthreads();

    // main loop: per step = COMPUTE; stage next B; prefetch A(s+2);
    // vmcnt(4) (own B-writes + prev A complete, newest 4 A outstanding); barrier.
#pragma unroll 1
    for (int s = 0; s < NSTEP; s += 2) {
        const int c2 = (s + 2 < NSTEP) ? s + 2 : NSTEP - 1;
        const int c3 = (s + 3 < NSTEP) ? s + 3 : NSTEP - 1;
        COMPUTE(s, aA, 0);
        STAGE_B(s + 1, 1);            // s+1 <= 23 always (s even, s <= 22)
        LOAD_A(aA, c2);
        asm volatile("s_waitcnt vmcnt(4)" ::: "memory");
        __builtin_amdgcn_s_barrier();
        asm volatile("" ::: "memory");
        COMPUTE(s + 1, aB, 1);
        STAGE_B(c2, 0);
        LOAD_A(aB, c3);
        asm volatile("s_waitcnt vmcnt(4)" ::: "memory");
        __builtin_amdgcn_s_barrier();
        asm volatile("" ::: "memory");
    }
#undef STAGE_B
#undef LOAD_A
#undef COMPUTE

    // per-pre-row stats: reduce over the 4 fq lanes sharing a row (same wave)
#pragma unroll
    for (int m = 0; m < 2; ++m) {
        ssr[m] += __shfl_xor(ssr[m], 16); ssr[m] += __shfl_xor(ssr[m], 32);
        z0r[m] += __shfl_xor(z0r[m], 16); z0r[m] += __shfl_xor(z0r[m], 32);
        z1r[m] += __shfl_xor(z1r[m], 16); z1r[m] += __shfl_xor(z1r[m], 32);
        if (fq == 0) {
            const int r  = wv * 32 + m * 16 + fr;
            const int rg = row0 + r;
            rn_s[r] = sqrtf(ssr[m]);
            float sc;
            if (rg < NVL_) sc = score[rg];
            else { float z = (z1r[m] + b1) - (z0r[m] + b0); sc = 1.f / (1.f + expf(-z)); }
            rsc_s[r] = sc;
        }
    }

    // epilogue: per-query online reductions over this block's TM pre-rows
    // (rn_s/rsc_s are own-wave-written; lab_s/qn_sh/qsc_sh published by prologue barrier)
#pragma unroll
    for (int n = 0; n < 8; ++n) {
        const int   c   = n * 16 + fr;
        const float qn  = qn_sh[c];
        const float qsc = qsc_sh[c];
        float mn = INFINITY, mx = -INFINITY, sss = 0.f, ssl = 0.f, s0 = 0.f, cnt = 0.f;
#pragma unroll
        for (int m = 0; m < 2; ++m) {
#pragma unroll
            for (int j = 0; j < 4; ++j) {
                const int r  = wv * 32 + m * 16 + fq * 4 + j;   // C row = pre row
                const int rg = row0 + r;
                const float d    = acc[m][n][j];
                const float cosv = d / fmaxf(rn_s[r] * qn, EPS_);
                float dd = rsc_s[r] - qsc; dd *= dd;
                const float sim   = cosv * (1.f - dd);
                const bool  sel   = (cosv >= THR_);
                const float sim_m = sel ? sim : -1.f;
                const bool  valid = (rg < NCOL_);
                mn = fminf(mn, valid ? sim_m : INFINITY);
                mx = fmaxf(mx, valid ? sim_m : -INFINITY);
                sss += sim_m + 1.f;                 // OOB rows: cos=0 -> exactly 0
                ssl += (sim_m + 1.f) * lab_s[r];
                if (sel) { s0 += sim; cnt += 1.f; }
            }
        }
        mn  = fminf(mn, __shfl_xor(mn, 16)); mn  = fminf(mn, __shfl_xor(mn, 32));
        mx  = fmaxf(mx, __shfl_xor(mx, 16)); mx  = fmaxf(mx, __shfl_xor(mx, 32));
        sss += __shfl_xor(sss, 16); sss += __shfl_xor(sss, 32);
        ssl += __shfl_xor(ssl, 16); ssl += __shfl_xor(ssl, 32);
        s0  += __shfl_xor(s0, 16);  s0  += __shfl_xor(s0, 32);
        cnt += __shfl_xor(cnt, 16); cnt += __shfl_xor(cnt, 32);
        if (fq == 0) {
            atomicMinF(&qmn[c], mn);
            atomicMaxF(&qmx[c], mx);
            atomicAdd(&qss[c],  sss);
            atomicAdd(&qssl[c], ssl);
            atomicAdd(&qs0[c],  s0);
            atomicAdd(&qcnt[c], cnt);
        }
    }
    __syncthreads();
    if (t < NQ_) {
        atomicMinF(ws + WS_MN + t, qmn[t]);
        atomicMaxF(ws + WS_MX + t, qmx[t]);
        atomicAdd(ws + WS_SS + t,  qss[t]);
        atomicAdd(ws + WS_SSL + t, qssl[t]);
        atomicAdd(ws + WS_S0 + t,  qs0[t]);
        atomicAdd(ws + WS_CNT + t, qcnt[t]);
    }
}

// ---------------- kernel 3: finalize outputs ----------------
__global__ void lpe_final(float* out, const float* ws) {
    int t = threadIdx.x;
    if (t < BS_) {
        out[t] = 1.f;            // exp_itm_label[:64]
        out[192 + t] = 1.f;      // exp_wo_alter_label[:64]
        out[385 + t] = 0.f;      // weights[:64]
    }
    if (t == 0) out[384] = 1.0f; // gamma = 131264/131264
    if (t >= BS_ && t < NVL_) {
        int i = t - BS_;
        float mn   = ws[WS_MN + i],  mx   = ws[WS_MX + i];
        float ssP  = ws[WS_SS + i],  sslP = ws[WS_SSL + i];
        float s0   = ws[WS_S0 + i],  cnt  = ws[WS_CNT + i];
        float Sl   = ws[WS_SL];
        float denomA = mx - mn + 1e-8f;
        float shift  = mn + 1.f;            // == 0 when min is the -1 sentinel
        float sumd = (ssP - (float)NCOL_ * shift) / denomA;
        float num  = (sslP - shift * Sl) / denomA;
        float wo   = num / (sumd + 1e-8f);
        float alt  = fmaxf(wo, 0.f);
        float w    = (cnt != 0.f) ? s0 / fmaxf(cnt, 1.f) : 0.f;
        float wt   = fmaxf(w - THR_, 0.f) / (1.f - THR_);
        out[BS_ + i] = alt;          // exp_itm_label[64:]
        out[192 + BS_ + i] = wo;     // exp_wo_alter_label[64:]
        out[385 + BS_ + i] = wt;     // weights[64:]
    }
}

extern "C" void kernel_launch(void* const* d_in, const int* in_sizes, int n_in,
                              void* d_out, int out_size, void* d_ws, size_t ws_size,
                              hipStream_t stream) {
    const float* vl    = (const float*)d_in[0];
    const float* score = (const float*)d_in[1];
    const float* itm   = (const float*)d_in[2];
    const float* queue = (const float*)d_in[3];
    const float* expl  = (const float*)d_in[4];
    const float* W     = (const float*)d_in[5];
    const float* b     = (const float*)d_in[6];
    float* out = (float*)d_out;
    float* ws  = (float*)d_ws;

    lpe_init<<<1, 256, 0, stream>>>(ws);
    lpe_prep<<<NQ_ + 256, 256, 0, stream>>>(vl, itm, expl, ws);
    const int nblk = (NCOL_ + TM - 1) / TM;   // 1026
    lpe_main<<<nblk, 256, 0, stream>>>(vl, score, itm, queue, expl, W, b, ws);
    lpe_final<<<1, 256, 0, stream>>>(out, ws);
}

// Round 11
// 138.378 us; speedup vs baseline: 2.1537x; 1.0383x over previous
//
#include <hip/hip_runtime.h>
#include <math.h>

namespace {
constexpr int   BS_   = 64;
constexpr int   D_    = 768;
constexpr int   NVL_  = 192;            // 3*BS rows of vl_embeddings
constexpr int   NQ_   = 128;            // query rows (vl[64:])
constexpr int   CAP_  = 131072;
constexpr int   NCOL_ = NVL_ + CAP_;    // 131264 (the PRE dimension)
constexpr float THR_  = 0.5f;
constexpr float EPS_  = 1e-8f;

// workspace float offsets
constexpr int WS_QN   = 0;    // 128 query norms
constexpr int WS_SL   = 128;  // 1   global label sum
constexpr int WS_MN   = 160;  // 128 per-query min(sim_m)
constexpr int WS_MX   = 288;  // 128 per-query max(sim_m)
constexpr int WS_SS   = 416;  // 128 per-query sum(sim_m + 1)
constexpr int WS_SSL  = 544;  // 128 per-query sum((sim_m + 1)*label)
constexpr int WS_S0   = 672;  // 128 per-query sum(sim where selected)
constexpr int WS_CNT  = 800;  // 128 per-query count(selected)
constexpr int WS_ZERO = 1024; // 768 zero floats (safe OOB source)
constexpr int WS_QBF  = 2048; // 49152 floats: q bf16, 24 tiles of 8192 B (swizzled LDS image)

constexpr int TM    = 128;    // pre-rows per block
constexpr int BK    = 32;     // k per step
constexpr int NSTEP = D_ / BK;   // 24
}

using bf16x8 = __attribute__((ext_vector_type(8))) short;
using f32x4  = __attribute__((ext_vector_type(4))) float;

__device__ inline void atomicMinF(float* addr, float v) {
    if (v >= 0.f) atomicMin((int*)addr, __float_as_int(v));
    else          atomicMax((unsigned int*)addr, __float_as_uint(v));
}
__device__ inline void atomicMaxF(float* addr, float v) {
    if (v >= 0.f) atomicMax((int*)addr, __float_as_int(v));
    else          atomicMin((unsigned int*)addr, __float_as_uint(v));
}
// pack two f32 -> two bf16 (RNE) in one u32 (integer path, used in prep)
__device__ inline unsigned pk2bf(float a, float b) {
    unsigned ua = __float_as_uint(a), ub = __float_as_uint(b);
    ua += 0x7fffu + ((ua >> 16) & 1u);
    ub += 0x7fffu + ((ub >> 16) & 1u);
    return (ua >> 16) | (ub & 0xffff0000u);
}
// single-instruction pack (lo = first operand); rounding-mode differences vs
// pk2bf perturb cos by <=2^-15 -- far under the 2e-2 tolerance / 0.29 margin.
__device__ inline unsigned cvtpk(float a, float b) {
    unsigned r;
    asm("v_cvt_pk_bf16_f32 %0, %1, %2" : "=v"(r) : "v"(a), "v"(b));
    return r;
}

// ---------------- kernel 0: init accumulators + zero pad buffer ----------------
__global__ void lpe_init(float* ws) {
    int t = threadIdx.x;
    if (t < NQ_) {
        ws[WS_MN + t]  = INFINITY;
        ws[WS_MX + t]  = -INFINITY;
        ws[WS_SS + t]  = 0.f;
        ws[WS_SSL + t] = 0.f;
        ws[WS_S0 + t]  = 0.f;
        ws[WS_CNT + t] = 0.f;
    }
    if (t == 0) ws[WS_SL] = 0.f;
    for (int i = t; i < D_; i += 256) ws[WS_ZERO + i] = 0.f;
}

// ---------------- kernel 1: query norms + q bf16 image + global label sum ----------------
__global__ void lpe_prep(const float* __restrict__ vl,
                         const float* __restrict__ itm,
                         const float* __restrict__ expl,
                         float* ws) {
    __shared__ float red[256];
    int b = blockIdx.x, t = threadIdx.x;
    if (b < NQ_) {
        const float* row = vl + (size_t)(BS_ + b) * D_;
        float s = 0.f;
        for (int k = t; k < D_; k += 256) { float v = row[k]; s += v * v; }
        red[t] = s; __syncthreads();
        for (int o = 128; o > 0; o >>= 1) { if (t < o) red[t] += red[t + o]; __syncthreads(); }
        if (t == 0) ws[WS_QN + b] = sqrtf(red[0]);
        // swizzled bf16 image: tile s (8192 B) = [row][64 B], byte = (kk*2) ^ ((row>>1 & 3)<<4)
        unsigned* qbf = (unsigned*)(ws + WS_QBF);
        const int sw = ((b >> 1) & 3) << 4;
        for (int k2 = t; k2 < 384; k2 += 256) {
            const int k = 2 * k2, tile = k >> 5, kk = k & 31;
            const unsigned val = pk2bf(row[k], row[k + 1]);
            const int byte = tile * 8192 + b * 64 + (((kk * 2) ^ sw) & 63);
            qbf[byte >> 2] = val;
        }
    } else {
        int idx = (b - NQ_) * 256 + t;
        float s = 0.f;
        for (int j = idx; j < NCOL_; j += 256 * 256)
            s += (j < NVL_) ? itm[j] : expl[j - NVL_];
        red[t] = s; __syncthreads();
        for (int o = 128; o > 0; o >>= 1) { if (t < o) red[t] += red[t + o]; __syncthreads(); }
        if (t == 0) atomicAdd(ws + WS_SL, red[0]);
    }
}

// ---------------- kernel 2: shared-B dbuf, counted vmcnt; fp32 VALU norms ----------------
// M = pre rows (128/block), N = 128 queries, K = 768, BK = 32.
__global__ __launch_bounds__(256, 3) void lpe_main(
        const float* __restrict__ vl, const float* __restrict__ score,
        const float* __restrict__ itm, const float* __restrict__ queue,
        const float* __restrict__ expl, const float* __restrict__ W,
        const float* __restrict__ bvec, float* ws) {
    __shared__ __align__(16) short Bs[2][NQ_][BK];     // shared B dbuf, 16 KB
    __shared__ __align__(16) float u_l[D_];            // u = W[:,1]-W[:,0], 3 KB
    __shared__ float rn_s[TM], rsc_s[TM], lab_s[TM];
    __shared__ float qn_sh[NQ_], qsc_sh[NQ_];
    __shared__ float qmn[NQ_], qmx[NQ_], qss[NQ_], qssl[NQ_], qs0[NQ_], qcnt[NQ_];

    const int t    = threadIdx.x;
    const int lane = t & 63;
    const int wv   = t >> 6;        // wave 0..3 computes rows wv*32..+31
    const int fr   = lane & 15;
    const int fq   = lane >> 4;
    const int row0 = blockIdx.x * TM;

    if (t < NQ_) {
        qn_sh[t]  = ws[WS_QN + t];
        qsc_sh[t] = score[BS_ + t];
        qmn[t] = INFINITY; qmx[t] = -INFINITY;
        qss[t] = 0.f; qssl[t] = 0.f; qs0[t] = 0.f; qcnt[t] = 0.f;
        int rg = row0 + t;
        lab_s[t] = (rg < NCOL_) ? ((rg < NVL_) ? itm[rg] : expl[rg - NVL_]) : 0.f;
    }
    for (int i = t; i < D_; i += 256) u_l[i] = W[2 * i + 1] - W[2 * i];
    const float bu = bvec[1] - bvec[0];
    const float* zb = ws + WS_ZERO;

    // per-lane A row pointers (frag: row = wv*32 + m*16 + fr, k-slice = fq*8)
    const float* ap[2];
#pragma unroll
    for (int m = 0; m < 2; ++m) {
        const int rg = row0 + wv * 32 + m * 16 + fr;
        const float* base = (rg < NVL_)  ? (vl + (size_t)rg * D_)
                          : (rg < NCOL_) ? (queue + (size_t)(rg - NVL_) * D_)
                                         : zb;
        ap[m] = base + fq * 8;
    }
    const char* qbf = (const char*)(ws + WS_QBF);

    float ssr[2] = {0.f, 0.f}, zr[2] = {0.f, 0.f};
    f32x4 acc[2][8];
#pragma unroll
    for (int m = 0; m < 2; ++m)
#pragma unroll
        for (int n = 0; n < 8; ++n) acc[m][n] = (f32x4){0.f, 0.f, 0.f, 0.f};

    float4 aA[2][2], aB[2][2];   // [m][half] A prefetch slots (static indexing only)

    // block-cooperative B staging: wave wv covers 2 KB of the 8 KB tile (2 insts)
#define STAGE_B(TILE, BUF) {                                                   \
    char* lb_ = (char*)&Bs[BUF][0][0] + wv * 2048;                             \
    const char* src_ = qbf + (size_t)(TILE) * 8192 + wv * 2048 + lane * 16;    \
    _Pragma("unroll")                                                          \
    for (int i_ = 0; i_ < 2; ++i_)                                             \
        __builtin_amdgcn_global_load_lds(                                      \
            (const __attribute__((address_space(1))) void*)(src_ + i_ * 1024), \
            (__attribute__((address_space(3))) void*)(lb_ + i_ * 1024),        \
            16, 0, 0); }

    // 4 vmem insts
#define LOAD_A(DST, S) {                                                       \
    _Pragma("unroll")                                                          \
    for (int m_ = 0; m_ < 2; ++m_) {                                           \
        const float* p_ = ap[m_] + (S) * BK;                                   \
        DST[m_][0] = *(const float4*)(p_);                                     \
        DST[m_][1] = *(const float4*)(p_ + 4);                                 \
    } }

#define COMPUTE(SB, AR, BUF) {                                                 \
    bf16x8 af_[2];                                                             \
    const float* up_ = &u_l[(SB) * 32 + fq * 8];                               \
    const float4 u0_ = *(const float4*)(up_);                                  \
    const float4 u1_ = *(const float4*)(up_ + 4);                              \
    _Pragma("unroll")                                                          \
    for (int m_ = 0; m_ < 2; ++m_) {                                           \
        const float4 v0_ = AR[m_][0];                                          \
        const float4 v1_ = AR[m_][1];                                          \
        ssr[m_] += v0_.x*v0_.x + v0_.y*v0_.y + v0_.z*v0_.z + v0_.w*v0_.w       \
                 + v1_.x*v1_.x + v1_.y*v1_.y + v1_.z*v1_.z + v1_.w*v1_.w;      \
        zr[m_]  += v0_.x*u0_.x + v0_.y*u0_.y + v0_.z*u0_.z + v0_.w*u0_.w       \
                 + v1_.x*u1_.x + v1_.y*u1_.y + v1_.z*u1_.z + v1_.w*u1_.w;      \
        union { unsigned u[4]; bf16x8 v; } cv_;                                \
        cv_.u[0] = cvtpk(v0_.x, v0_.y); cv_.u[1] = cvtpk(v0_.z, v0_.w);        \
        cv_.u[2] = cvtpk(v1_.x, v1_.y); cv_.u[3] = cvtpk(v1_.z, v1_.w);        \
        af_[m_] = cv_.v;                                                       \
    }                                                                          \
    const char* bb_ = (const char*)&Bs[BUF][0][0];                             \
    _Pragma("unroll")                                                          \
    for (int n_ = 0; n_ < 8; ++n_) {                                           \
        const int rb_ = n_ * 16 + fr;                                          \
        bf16x8 bv_ = *(const bf16x8*)(bb_ + rb_ * 64 + 16 * (fq ^ ((rb_ >> 1) & 3))); \
        acc[0][n_] = __builtin_amdgcn_mfma_f32_16x16x32_bf16(af_[0], bv_, acc[0][n_], 0, 0, 0); \
        acc[1][n_] = __builtin_amdgcn_mfma_f32_16x16x32_bf16(af_[1], bv_, acc[1][n_], 0, 0, 0); \
    } }

    // prologue: B(0) -> buf0; A(0) -> aA; A(1) -> aB; full drain publishes init/u/B0
    STAGE_B(0, 0);
    LOAD_A(aA, 0);
    LOAD_A(aB, 1);
    __syncthreads();

    // main loop: per step = COMPUTE; stage next B; prefetch A(s+2);
    // vmcnt(4) (own B-writes + prev A complete, newest 4 A outstanding); barrier.
#pragma unroll 1
    for (int s = 0; s < NSTEP; s += 2) {
        const int c2 = (s + 2 < NSTEP) ? s + 2 : NSTEP - 1;
        const int c3 = (s + 3 < NSTEP) ? s + 3 : NSTEP - 1;
        COMPUTE(s, aA, 0);
        STAGE_B(s + 1, 1);            // s+1 <= 23 always (s even, s <= 22)
        LOAD_A(aA, c2);
        asm volatile("s_waitcnt vmcnt(4)" ::: "memory");
        __builtin_amdgcn_s_barrier();
        asm volatile("" ::: "memory");
        COMPUTE(s + 1, aB, 1);
        STAGE_B(c2, 0);
        LOAD_A(aB, c3);
        asm volatile("s_waitcnt vmcnt(4)" ::: "memory");
        __builtin_amdgcn_s_barrier();
        asm volatile("" ::: "memory");
    }
#undef STAGE_B
#undef LOAD_A
#undef COMPUTE

    // per-pre-row stats: reduce over the 4 fq lanes sharing a row (same wave)
#pragma unroll
    for (int m = 0; m < 2; ++m) {
        ssr[m] += __shfl_xor(ssr[m], 16); ssr[m] += __shfl_xor(ssr[m], 32);
        zr[m]  += __shfl_xor(zr[m], 16);  zr[m]  += __shfl_xor(zr[m], 32);
        if (fq == 0) {
            const int r  = wv * 32 + m * 16 + fr;
            const int rg = row0 + r;
            rn_s[r] = sqrtf(ssr[m]);
            float sc;
            if (rg < NVL_) sc = score[rg];
            else { float z = zr[m] + bu; sc = 1.f / (1.f + expf(-z)); }
            rsc_s[r] = sc;
        }
    }

    // epilogue: per-query online reductions over this block's TM pre-rows
    // (rn_s/rsc_s own-wave-written; lab_s/qn_sh/qsc_sh published by prologue barrier)
#pragma unroll
    for (int n = 0; n < 8; ++n) {
        const int   c   = n * 16 + fr;
        const float qn  = qn_sh[c];
        const float qsc = qsc_sh[c];
        float mn = INFINITY, mx = -INFINITY, sss = 0.f, ssl = 0.f, s0 = 0.f, cnt = 0.f;
#pragma unroll
        for (int m = 0; m < 2; ++m) {
#pragma unroll
            for (int j = 0; j < 4; ++j) {
                const int r  = wv * 32 + m * 16 + fq * 4 + j;   // C row = pre row
                const int rg = row0 + r;
                const float d    = acc[m][n][j];
                const float cosv = d / fmaxf(rn_s[r] * qn, EPS_);
                float dd = rsc_s[r] - qsc; dd *= dd;
                const float sim   = cosv * (1.f - dd);
                const bool  sel   = (cosv >= THR_);
                const float sim_m = sel ? sim : -1.f;
                const bool  valid = (rg < NCOL_);
                mn = fminf(mn, valid ? sim_m : INFINITY);
                mx = fmaxf(mx, valid ? sim_m : -INFINITY);
                sss += sim_m + 1.f;                 // OOB rows: cos=0 -> exactly 0
                ssl += (sim_m + 1.f) * lab_s[r];
                if (sel) { s0 += sim; cnt += 1.f; }
            }
        }
        mn  = fminf(mn, __shfl_xor(mn, 16)); mn  = fminf(mn, __shfl_xor(mn, 32));
        mx  = fmaxf(mx, __shfl_xor(mx, 16)); mx  = fmaxf(mx, __shfl_xor(mx, 32));
        sss += __shfl_xor(sss, 16); sss += __shfl_xor(sss, 32);
        ssl += __shfl_xor(ssl, 16); ssl += __shfl_xor(ssl, 32);
        s0  += __shfl_xor(s0, 16);  s0  += __shfl_xor(s0, 32);
        cnt += __shfl_xor(cnt, 16); cnt += __shfl_xor(cnt, 32);
        if (fq == 0) {
            atomicMinF(&qmn[c], mn);
            atomicMaxF(&qmx[c], mx);
            atomicAdd(&qss[c],  sss);
            atomicAdd(&qssl[c], ssl);
            atomicAdd(&qs0[c],  s0);
            atomicAdd(&qcnt[c], cnt);
        }
    }
    __syncthreads();
    if (t < NQ_) {
        atomicMinF(ws + WS_MN + t, qmn[t]);
        atomicMaxF(ws + WS_MX + t, qmx[t]);
        atomicAdd(ws + WS_SS + t,  qss[t]);
        atomicAdd(ws + WS_SSL + t, qssl[t]);
        atomicAdd(ws + WS_S0 + t,  qs0[t]);
        atomicAdd(ws + WS_CNT + t, qcnt[t]);
    }
}

// ---------------- kernel 3: finalize outputs ----------------
__global__ void lpe_final(float* out, const float* ws) {
    int t = threadIdx.x;
    if (t < BS_) {
        out[t] = 1.f;            // exp_itm_label[:64]
        out[192 + t] = 1.f;      // exp_wo_alter_label[:64]
        out[385 + t] = 0.f;      // weights[:64]
    }
    if (t == 0) out[384] = 1.0f; // gamma = 131264/131264
    if (t >= BS_ && t < NVL_) {
        int i = t - BS_;
        float mn   = ws[WS_MN + i],  mx   = ws[WS_MX + i];
        float ssP  = ws[WS_SS + i],  sslP = ws[WS_SSL + i];
        float s0   = ws[WS_S0 + i],  cnt  = ws[WS_CNT + i];
        float Sl   = ws[WS_SL];
        float denomA = mx - mn + 1e-8f;
        float shift  = mn + 1.f;            // == 0 when min is the -1 sentinel
        float sumd = (ssP - (float)NCOL_ * shift) / denomA;
        float num  = (sslP - shift * Sl) / denomA;
        float wo   = num / (sumd + 1e-8f);
        float alt  = fmaxf(wo, 0.f);
        float w    = (cnt != 0.f) ? s0 / fmaxf(cnt, 1.f) : 0.f;
        float wt   = fmaxf(w - THR_, 0.f) / (1.f - THR_);
        out[BS_ + i] = alt;          // exp_itm_label[64:]
        out[192 + BS_ + i] = wo;     // exp_wo_alter_label[64:]
        out[385 + BS_ + i] = wt;     // weights[64:]
    }
}

extern "C" void kernel_launch(void* const* d_in, const int* in_sizes, int n_in,
                              void* d_out, int out_size, void* d_ws, size_t ws_size,
                              hipStream_t stream) {
    const float* vl    = (const float*)d_in[0];
    const float* score = (const float*)d_in[1];
    const float* itm   = (const float*)d_in[2];
    const float* queue = (const float*)d_in[3];
    const float* expl  = (const float*)d_in[4];
    const float* W     = (const float*)d_in[5];
    const float* b     = (const float*)d_in[6];
    float* out = (float*)d_out;
    float* ws  = (float*)d_ws;

    lpe_init<<<1, 256, 0, stream>>>(ws);
    lpe_prep<<<NQ_ + 256, 256, 0, stream>>>(vl, itm, expl, ws);
    const int nblk = (NCOL_ + TM - 1) / TM;   // 1026
    lpe_main<<<nblk, 256, 0, stream>>>(vl, score, itm, queue, expl, W, b, ws);
    lpe_final<<<1, 256, 0, stream>>>(out, ws);
}